// Round 1
// baseline (857.752 us; speedup 1.0000x reference)
//
#include <hip/hip_runtime.h>
#include <math.h>

// Problem constants (from reference):
// B=4480, L=7, H=8, E=64, S=56, D=64, N_STATIONS=35
// out[b,l,h,d] = sum_s A[b,h,l,s] * ( P[n,l,s]*V[b,s,h,d] + (1-P[n,l,s])*0.1*Z[b,s,h,d] )
// with A = softmax(QK^T / 8) over s, n = b % 35,
// Z (noise) flat layout identical to V since b = ab*35 + n.

namespace {
constexpr int kL = 7;
constexpr int kH = 8;
constexpr int kE = 64;
constexpr int kS = 56;
constexpr int kD = 64;
constexpr int kN = 35;
constexpr float kScale = 0.125f;      // 1/sqrt(64)
constexpr float kNoiseStd = 0.1f;
constexpr int kWaves = 4;             // waves per block, one (b,h) pair per wave
}

__global__ __launch_bounds__(256, 2)
void fullattn_fused_kernel(const float* __restrict__ Q,
                           const float* __restrict__ K,
                           const float* __restrict__ V,
                           const float* __restrict__ P,
                           const float* __restrict__ Z,
                           float* __restrict__ O)
{
    // Per-wave LDS: B1 = A*P, B2 = A*(1-P)*0.1  (scores staged in sB1 first)
    __shared__ float sB1[kWaves][kL * kS];
    __shared__ float sB2[kWaves][kL * kS];

    const int tid  = threadIdx.x;
    const int wid  = tid >> 6;
    const int lane = tid & 63;
    const int sl   = lane >> 4;   // 0..3  : s sub-row within a quad of rows
    const int c    = lane & 15;   // 0..15 : float4 column within the 64-dim

    const int pair = blockIdx.x * kWaves + wid;   // (b,h), grid sized exactly
    const int b = pair >> 3;
    const int h = pair & 7;
    const int n = b % kN;

    const float* qb = Q + ((size_t)b * kL * kH + h) * kE;
    const float* kb = K + ((size_t)b * kS * kH + h) * kE;
    const float* vb = V + ((size_t)b * kS * kH + h) * kD;
    const float* zb = Z + ((size_t)b * kS * kH + h) * kD;

    // ---- Q into registers: q4[l] = Q[b,l,h,4c..4c+3] (256B/load, broadcast over sl groups)
    float4 q4[kL];
    #pragma unroll
    for (int l = 0; l < kL; ++l)
        q4[l] = *reinterpret_cast<const float4*>(qb + l * (kH * kE) + 4 * c);

    // ---- K into registers: k4[i] = K[b, 4i+sl, h, 4c..4c+3] (16 full lines / instruction)
    float4 k4[kS / 4];
    #pragma unroll
    for (int i = 0; i < kS / 4; ++i)
        k4[i] = *reinterpret_cast<const float4*>(kb + (4 * i + sl) * (kH * kE) + 4 * c);

    // ---- scores[l][s] = Q[l]·K[s]: 4-wide partial dot + 16-lane butterfly over c
    float* sbuf = sB1[wid];
    #pragma unroll
    for (int i = 0; i < kS / 4; ++i) {
        #pragma unroll
        for (int l = 0; l < kL; ++l) {
            float p = q4[l].x * k4[i].x + q4[l].y * k4[i].y
                    + q4[l].z * k4[i].z + q4[l].w * k4[i].w;
            p += __shfl_xor(p, 1);
            p += __shfl_xor(p, 2);
            p += __shfl_xor(p, 4);
            p += __shfl_xor(p, 8);
            if (c == 0) sbuf[l * kS + 4 * i + sl] = p;
        }
    }
    __syncthreads();

    // ---- softmax over s (lane = s), fold in station prob matrix
    const float* prow = P + (size_t)n * kL * kS;
    #pragma unroll
    for (int l = 0; l < kL; ++l) {
        float x = (lane < kS) ? sbuf[l * kS + lane] * kScale : -INFINITY;
        float m = x;
        m = fmaxf(m, __shfl_xor(m, 1));
        m = fmaxf(m, __shfl_xor(m, 2));
        m = fmaxf(m, __shfl_xor(m, 4));
        m = fmaxf(m, __shfl_xor(m, 8));
        m = fmaxf(m, __shfl_xor(m, 16));
        m = fmaxf(m, __shfl_xor(m, 32));
        float e = (lane < kS) ? __expf(x - m) : 0.0f;
        float sum = e;
        sum += __shfl_xor(sum, 1);
        sum += __shfl_xor(sum, 2);
        sum += __shfl_xor(sum, 4);
        sum += __shfl_xor(sum, 8);
        sum += __shfl_xor(sum, 16);
        sum += __shfl_xor(sum, 32);
        float a = e / sum;
        if (lane < kS) {
            float p = prow[l * kS + lane];
            p = fminf(fmaxf(p, 0.0f), 1.0f);
            sB1[wid][l * kS + lane] = a * p;                      // overwrites scores row l
            sB2[wid][l * kS + lane] = a * (1.0f - p) * kNoiseStd;
        }
    }
    __syncthreads();

    // ---- out[l][d] = sum_s B1[l][s]*V[s][d] + B2[l][s]*Z[s][d]
    float4 acc[kL];
    #pragma unroll
    for (int l = 0; l < kL; ++l) acc[l] = make_float4(0.f, 0.f, 0.f, 0.f);

    const float* b1w = sB1[wid];
    const float* b2w = sB2[wid];
    #pragma unroll
    for (int i = 0; i < kS / 4; ++i) {
        const int s = 4 * i + sl;
        const float4 v4 = *reinterpret_cast<const float4*>(vb + s * (kH * kD) + 4 * c);
        const float4 z4 = *reinterpret_cast<const float4*>(zb + s * (kH * kD) + 4 * c);
        #pragma unroll
        for (int l = 0; l < kL; ++l) {
            const float w1 = b1w[l * kS + s];
            const float w2 = b2w[l * kS + s];
            acc[l].x += w1 * v4.x + w2 * z4.x;
            acc[l].y += w1 * v4.y + w2 * z4.y;
            acc[l].z += w1 * v4.z + w2 * z4.z;
            acc[l].w += w1 * v4.w + w2 * z4.w;
        }
    }

    // ---- reduce the 4 sl-groups, lanes 0..15 store 256B coalesced per l
    #pragma unroll
    for (int l = 0; l < kL; ++l) {
        float4 a = acc[l];
        a.x += __shfl_xor(a.x, 16);
        a.y += __shfl_xor(a.y, 16);
        a.z += __shfl_xor(a.z, 16);
        a.w += __shfl_xor(a.w, 16);
        a.x += __shfl_xor(a.x, 32);
        a.y += __shfl_xor(a.y, 32);
        a.z += __shfl_xor(a.z, 32);
        a.w += __shfl_xor(a.w, 32);
        if (sl == 0) {
            *reinterpret_cast<float4*>(
                O + (((size_t)b * kL + l) * kH + h) * kD + 4 * c) = a;
        }
    }
}

extern "C" void kernel_launch(void* const* d_in, const int* in_sizes, int n_in,
                              void* d_out, int out_size, void* d_ws, size_t ws_size,
                              hipStream_t stream) {
    const float* Q = (const float*)d_in[0];  // queries  [4480,7,8,64]
    const float* K = (const float*)d_in[1];  // keys     [4480,56,8,64]
    const float* V = (const float*)d_in[2];  // values   [4480,56,8,64]
    const float* P = (const float*)d_in[3];  // prob     [35,7,56]
    const float* Z = (const float*)d_in[4];  // noise    [128,35,56,8,64] == [4480,56,8,64]
    float* O = (float*)d_out;                // out      [4480,7,8,64]

    const int pairs = 4480 * 8;              // (b,h) pairs
    dim3 grid(pairs / kWaves);               // 8960 blocks x 256 threads
    fullattn_fused_kernel<<<grid, 256, 0, stream>>>(Q, K, V, P, Z, O);
}